// Round 11
// baseline (151.577 us; speedup 1.0000x reference)
//
#include <hip/hip_runtime.h>
#include <hip/hip_bf16.h>
#include <math.h>

// Problem constants
#define BATCH   2048
#define TWO_B   4096
#define DIM     1024
#define NBLK3   4096          // 64x64 grid of 64x64 tiles, 1 wave per block
// 1 / (0.07 * ln(2)) : exp(s/T) = exp2(s * INV_T_LOG2E)
#define INV_T_LOG2E 20.60991907f
#define INV_T       14.285714285714286f

// s_waitcnt simm16: vmcnt[3:0]|[15:14], expcnt[6:4], lgkmcnt[11:8]
#define WAITCNT_VM0   0x0F70   // vmcnt(0), lgkm/exp don't-care
#define WAITCNT_LGKM0 0xC07F   // lgkmcnt(0), vm/exp don't-care

typedef float f32x4 __attribute__((ext_vector_type(4)));
typedef long  i64x2 __attribute__((ext_vector_type(2)));

__device__ __forceinline__ void load_lds16(const void* g, void* l) {
    __builtin_amdgcn_global_load_lds(
        (const __attribute__((address_space(1))) void*)g,
        (__attribute__((address_space(3))) void*)l,
        16, 0, 0);
}

// ---------------------------------------------------------------------------
// Kernel 1: L2-normalize 4096 rows -> fp8 e4m3 z[4096][1024] (4 MB).
// Wave-per-row; zero-inits rowsum + completion counter. No fences.
// ---------------------------------------------------------------------------
__global__ __launch_bounds__(256) void normalize_kernel(
        const float* __restrict__ feat, char* __restrict__ z,
        float* __restrict__ rowsum, unsigned int* __restrict__ counter) {
    const int lane = threadIdx.x & 63;
    const int row  = blockIdx.x * 4 + (threadIdx.x >> 6);
    if (lane == 0) rowsum[row] = 0.0f;
    if (blockIdx.x == 0 && threadIdx.x == 0) *counter = 0u;

    const float* src = feat + (row < BATCH ? (size_t)row * (2 * DIM)
                                           : (size_t)(row - BATCH) * (2 * DIM) + DIM);
    float4 v[4];
    float ss = 0.0f;
    #pragma unroll
    for (int t = 0; t < 4; ++t) {
        v[t] = ((const float4*)src)[t * 64 + lane];
        ss += v[t].x * v[t].x + v[t].y * v[t].y + v[t].z * v[t].z + v[t].w * v[t].w;
    }
    #pragma unroll
    for (int off = 32; off; off >>= 1) ss += __shfl_xor(ss, off, 64);
    const float scale = 1.0f / fmaxf(sqrtf(ss), 1e-12f);
    int4 o;
    int* op = (int*)&o;
    #pragma unroll
    for (int t = 0; t < 4; ++t) {
        int lo = __builtin_amdgcn_cvt_pk_fp8_f32(v[t].x * scale, v[t].y * scale, 0, false);
        op[t]  = __builtin_amdgcn_cvt_pk_fp8_f32(v[t].z * scale, v[t].w * scale, lo, true);
    }
    ((int4*)(z + (size_t)row * DIM))[lane] = o;   // 64 lanes x 16 B = one row
}

// ---------------------------------------------------------------------------
// Kernel 2: sim = z z^T in fp8 e4m3. R11: WAVE-PRIVATE BLOCKS — 64 threads,
// 64x64 tile, 4096 blocks = 16 independent waves/CU (m114 TLP), ZERO
// barriers (LDS is wave-private, so no __syncthreads -> no vmcnt(0) drain,
// the mechanism R5/R7/R9 proved unfixable within multi-wave blocks).
// K-loop (BK=64, single 8 KB buffer, register-level double buffer):
//   vmcnt(0)               — staging of tile t complete (covered by MFMAs)
//   ds_read 8xb128 -> regs — the ENTIRE tile, each byte exactly once
//   lgkmcnt(0)             — frags safely in VGPRs
//   issue staging tile t+1 — same buffer (regs hold tile t)
//   32 MFMAs               — cover staging latency
// XOR swizzle (R6-proven, 0 conflicts): slot s of row r holds K-seg
// s^((r>>1)&3); read slot q^((mn>>1)&3); same K-permutation for A and B.
// XCD swizzle: 16x32-tile region per XCD = 3 MB < 4 MB L2.
// Epilogue: LDS-transpose into (reused) smem + one coalesced 64-lane
// atomicAdd; fence-free last-block finalize (shfl broadcast, no LDS flag).
// ---------------------------------------------------------------------------
__global__ __launch_bounds__(64, 4) void gemm_fused(
        const char* __restrict__ z,
        float* __restrict__ rowsum,
        float* __restrict__ positives,
        unsigned int* __restrict__ counter,
        float* __restrict__ out) {
    __shared__ char smem[8192];      // sA 4 KB | sB 4 KB; reused as epilogue scratch

    // XCD-aware swizzle: id&7 = round-robin XCD; 16x32-tile region per XCD
    const int bid = blockIdx.x;
    const int xcd = bid & 7;
    const int t9  = bid >> 3;                   // 0..511 within region
    const int by  = (xcd >> 1) * 16 + (t9 & 15);
    const int bx  = (xcd & 1) * 32 + (t9 >> 4);
    const int rb  = by * 64;
    const int cb  = bx * 64;

    const int lane = threadIdx.x;    // single wave
    const int q    = lane >> 4;      // quad 0..3 (16-B K-segment)
    const int mn   = lane & 15;

    char* sA = smem;
    char* sB = smem + 4096;

    f32x4 acc[4][4] = {};

    // staging: chunk = 16 rows x 64 B = 1 KB; 4 chunks per matrix.
    // lane l: row l>>2, slot l&3, fetches K-seg (l&3)^((l>>3)&3).
    const int lrow  = lane >> 2;
    const int lsegb = ((lane & 3) ^ ((lane >> 3) & 3)) * 16;
    const int rslot = (q ^ ((mn >> 1) & 3)) * 16;   // read slot, byte offset

    // per-chunk global offsets (K advances by +k0)
    size_t aoff[4], boff[4];
    #pragma unroll
    for (int c = 0; c < 4; ++c) {
        aoff[c] = (size_t)(rb + c * 16 + lrow) * DIM + lsegb;
        boff[c] = (size_t)(cb + c * 16 + lrow) * DIM + lsegb;
    }

    // stage K-tile 0
    #pragma unroll
    for (int c = 0; c < 4; ++c) {
        load_lds16(z + aoff[c], sA + c * 1024);
        load_lds16(z + boff[c], sB + c * 1024);
    }

    for (int t = 0; t < 16; ++t) {
        __builtin_amdgcn_s_waitcnt(WAITCNT_VM0);   // tile t staged
        asm volatile("" ::: "memory");

        i64x2 af[4], bf[4];
        #pragma unroll
        for (int i = 0; i < 4; ++i) {
            af[i] = *(const i64x2*)&sA[(i * 16 + mn) * 64 + rslot];
            bf[i] = *(const i64x2*)&sB[(i * 16 + mn) * 64 + rslot];
        }
        __builtin_amdgcn_s_waitcnt(WAITCNT_LGKM0); // frags in VGPRs
        asm volatile("" ::: "memory");

        if (t < 15) {                              // stage tile t+1 (same buffer)
            const int k0 = (t + 1) * 64;
            #pragma unroll
            for (int c = 0; c < 4; ++c) {
                load_lds16(z + aoff[c] + k0, sA + c * 1024);
                load_lds16(z + boff[c] + k0, sB + c * 1024);
            }
        }

        #pragma unroll
        for (int i = 0; i < 4; ++i)
            #pragma unroll
            for (int j = 0; j < 4; ++j) {
                acc[i][j] = __builtin_amdgcn_mfma_f32_16x16x32_fp8_fp8(
                                af[i].x, bf[j].x, acc[i][j], 0, 0, 0);
                acc[i][j] = __builtin_amdgcn_mfma_f32_16x16x32_fp8_fp8(
                                af[i].y, bf[j].y, acc[i][j], 0, 0, 0);
            }
    }

    // ---- Epilogue (C/D layout col = lane&15, row = (lane>>4)*4 + reg) ----
    // smem reuse as 64x20 float transpose scratch (wave-private; compiler
    // orders the ds ops — plain C accesses to the same shared array).
    float* ep = (float*)smem;
    #pragma unroll
    for (int i = 0; i < 4; ++i) {
        #pragma unroll
        for (int reg = 0; reg < 4; ++reg) {
            const int r  = rb + i * 16 + q * 4 + reg;
            const int pc = (r + BATCH) & (TWO_B - 1);
            float local = 0.0f;
            #pragma unroll
            for (int j = 0; j < 4; ++j) {
                const int c = cb + j * 16 + mn;
                const float s = acc[i][j][reg];
                if (c == pc)   // unique writer per r
                    __hip_atomic_store(&positives[r], s, __ATOMIC_RELAXED,
                                       __HIP_MEMORY_SCOPE_AGENT);
                local += (c == r) ? 0.0f : exp2f(s * INV_T_LOG2E);
            }
            ep[(i * 16 + q * 4 + reg) * 20 + mn] = local;
        }
    }
    {
        const float4 p0 = *(const float4*)&ep[lane * 20 + 0];
        const float4 p1 = *(const float4*)&ep[lane * 20 + 4];
        const float4 p2 = *(const float4*)&ep[lane * 20 + 8];
        const float4 p3 = *(const float4*)&ep[lane * 20 + 12];
        const float tot = (p0.x + p0.y + p0.z + p0.w) + (p1.x + p1.y + p1.z + p1.w)
                        + (p2.x + p2.y + p2.z + p2.w) + (p3.x + p3.y + p3.z + p3.w);
        atomicAdd(&rowsum[rb + lane], tot);   // coalesced 64-lane atomic
    }

    // ---- fence-free last-block finalize (single wave, shfl broadcast) ----
    unsigned int old = 0u;
    if (lane == 0)
        old = __hip_atomic_fetch_add(counter, 1u, __ATOMIC_RELAXED,
                                     __HIP_MEMORY_SCOPE_AGENT);
    old = __shfl(old, 0, 64);
    if (old == NBLK3 - 1) {
        float acc2 = 0.0f;
        for (int r = lane; r < TWO_B; r += 64) {
            float rs = __hip_atomic_load(&rowsum[r], __ATOMIC_RELAXED,
                                         __HIP_MEMORY_SCOPE_AGENT);
            float p  = __hip_atomic_load(&positives[r], __ATOMIC_RELAXED,
                                         __HIP_MEMORY_SCOPE_AGENT);
            acc2 += logf(rs) - p * INV_T;
        }
        #pragma unroll
        for (int off = 32; off; off >>= 1) acc2 += __shfl_down(acc2, off, 64);
        if (lane == 0) out[0] = acc2 * (1.0f / TWO_B);
    }
}

extern "C" void kernel_launch(void* const* d_in, const int* in_sizes, int n_in,
                              void* d_out, int out_size, void* d_ws, size_t ws_size,
                              hipStream_t stream) {
    const float* feat = (const float*)d_in[0];
    char* ws = (char*)d_ws;

    // workspace: z fp8[4096][1024] (4 MB) | rowsum f32[4096] | positives f32[4096] | counter
    char* zq              = ws;
    float* rowsum         = (float*)(ws + (size_t)TWO_B * DIM);
    float* positives      = rowsum + TWO_B;
    unsigned int* counter = (unsigned int*)(positives + TWO_B);
    float* out            = (float*)d_out;

    normalize_kernel<<<TWO_B / 4, 256, 0, stream>>>(feat, zq, rowsum, counter);
    gemm_fused<<<NBLK3, 64, 0, stream>>>(zq, rowsum, positives, counter, out);
}

// Round 12
// 134.450 us; speedup vs baseline: 1.1274x; 1.1274x over previous
//
#include <hip/hip_runtime.h>
#include <hip/hip_bf16.h>
#include <math.h>

// Problem constants
#define BATCH   2048
#define TWO_B   4096
#define DIM     1024
#define NBLK2   1024          // 32x32 grid of 128x128 tiles
// 1 / (0.07 * ln(2)) : exp(s/T) = exp2(s * INV_T_LOG2E)
#define INV_T_LOG2E 20.60991907f
#define INV_T       14.285714285714286f
#define SCALE_ONE   0x7F7F7F7F   // E8M0 unity scale in every byte

typedef float f32x16 __attribute__((ext_vector_type(16)));
typedef int   v8i    __attribute__((ext_vector_type(8)));

__device__ __forceinline__ void load_lds16(const void* g, void* l) {
    __builtin_amdgcn_global_load_lds(
        (const __attribute__((address_space(1))) void*)g,
        (__attribute__((address_space(3))) void*)l,
        16, 0, 0);
}

// ---------------------------------------------------------------------------
// Kernel 1: L2-normalize 4096 rows -> fp8 e4m3 z[4096][1024] (4 MB).
// Wave-per-row; zero-inits rowsum + completion counter. No fences.
// ---------------------------------------------------------------------------
__global__ __launch_bounds__(256) void normalize_kernel(
        const float* __restrict__ feat, char* __restrict__ z,
        float* __restrict__ rowsum, unsigned int* __restrict__ counter) {
    const int lane = threadIdx.x & 63;
    const int row  = blockIdx.x * 4 + (threadIdx.x >> 6);
    if (lane == 0) rowsum[row] = 0.0f;
    if (blockIdx.x == 0 && threadIdx.x == 0) *counter = 0u;

    const float* src = feat + (row < BATCH ? (size_t)row * (2 * DIM)
                                           : (size_t)(row - BATCH) * (2 * DIM) + DIM);
    float4 v[4];
    float ss = 0.0f;
    #pragma unroll
    for (int t = 0; t < 4; ++t) {
        v[t] = ((const float4*)src)[t * 64 + lane];
        ss += v[t].x * v[t].x + v[t].y * v[t].y + v[t].z * v[t].z + v[t].w * v[t].w;
    }
    #pragma unroll
    for (int off = 32; off; off >>= 1) ss += __shfl_xor(ss, off, 64);
    const float scale = 1.0f / fmaxf(sqrtf(ss), 1e-12f);
    int4 o;
    int* op = (int*)&o;
    #pragma unroll
    for (int t = 0; t < 4; ++t) {
        int lo = __builtin_amdgcn_cvt_pk_fp8_f32(v[t].x * scale, v[t].y * scale, 0, false);
        op[t]  = __builtin_amdgcn_cvt_pk_fp8_f32(v[t].z * scale, v[t].w * scale, lo, true);
    }
    ((int4*)(z + (size_t)row * DIM))[lane] = o;   // 64 lanes x 16 B = one row
}

// ---------------------------------------------------------------------------
// Kernel 2: sim = z z^T in fp8 e4m3 via MX-SCALED MFMA (unit scales).
// R12 = R8's proven-best shell (128x128 tile, 4 waves, BK=64, dbuf LDS,
// XOR swizzle -> 0 conflicts, XCD region swizzle, fence-free finalize)
// with the inner product switched to mfma_scale_f32_32x32x64_f8f6f4:
// 16 MFMA/block-iter (65536 FLOP each, ~8.6 cyc/CU, m59: 4686 TF) instead
// of 128x 16x16x32 (~627 cyc matrix-pipe/iter -> ~137).
// Fragment fetch: lane l = row (lane&31), k in [32*(lane>>5), +32); our
// swizzled slots (2h)^sw,(2h+1)^sw retrieve exactly segs 2h,2h+1 = that
// canonical contiguous k-range in order (byte-exact canonical operands).
// C/D layout (32x32, m74/m101): col=lane&31, row=(reg&3)+8*(reg>>2)+4*h.
// ---------------------------------------------------------------------------
__global__ __launch_bounds__(256) void gemm_fused(
        const char* __restrict__ z,
        float* __restrict__ rowsum,
        float* __restrict__ positives,
        unsigned int* __restrict__ counter,
        float* __restrict__ out) {
    __shared__ char smem[32768];     // 2x8KB sA dbuf | 2x8KB sB dbuf

    // XCD-aware swizzle: id&7 = round-robin XCD; 8x16 block region per XCD
    const int bid = blockIdx.x;
    const int xcd = bid & 7;
    const int t8  = bid >> 3;                   // 0..127 within region
    const int by  = (xcd >> 1) * 8 + (t8 & 7);
    const int bx  = (xcd & 1) * 16 + (t8 >> 3);
    const int rb  = by * 128;
    const int cb  = bx * 128;

    const int tid  = threadIdx.x;
    const int lane = tid & 63;
    const int wv   = tid >> 6;       // wave 0..3
    const int wr   = wv >> 1;        // wave row (0..1) -> 64-row subtile
    const int wc   = wv & 1;         // wave col (0..1) -> 64-col subtile
    const int m31  = lane & 31;      // row/col within 32-tile
    const int h    = lane >> 5;      // k-half selector (k in [32h, 32h+32))

    char* sA0 = smem;                // sA[buf] = smem + buf*8192
    char* sB0 = smem + 16384;        // sB[buf] = smem + 16384 + buf*8192

    f32x16 acc[2][2] = {};

    const int lrow  = lane >> 2;                       // staging row in 16-row chunk
    const int lsegb = ((lane & 3) ^ ((lane >> 3) & 3)) * 16;   // fetch-side XOR swizzle
    // fragment read slots: row swizzle sw = bits 1..2 of row = of lane
    const int sw    = (lane >> 1) & 3;
    const int slot0 = ((2 * h) ^ sw) * 16;
    const int slot1 = ((2 * h + 1) ^ sw) * 16;

    // per-wave staging chunks: ci = 2*wv, 2*wv+1 (16 rows x 64 B = 1 KB each)
    const size_t aoff0 = (size_t)(rb + (wv * 2 + 0) * 16 + lrow) * DIM + lsegb;
    const size_t aoff1 = (size_t)(rb + (wv * 2 + 1) * 16 + lrow) * DIM + lsegb;
    const size_t boff0 = (size_t)(cb + (wv * 2 + 0) * 16 + lrow) * DIM + lsegb;
    const size_t boff1 = (size_t)(cb + (wv * 2 + 1) * 16 + lrow) * DIM + lsegb;

    // preload K-tile 0 into buffer 0
    load_lds16(z + aoff0, sA0 + (wv * 2 + 0) * 1024);
    load_lds16(z + aoff1, sA0 + (wv * 2 + 1) * 1024);
    load_lds16(z + boff0, sB0 + (wv * 2 + 0) * 1024);
    load_lds16(z + boff1, sB0 + (wv * 2 + 1) * 1024);
    __syncthreads();

    int cur = 0;
    for (int k0 = 64; k0 <= DIM; k0 += 64) {
        if (k0 < DIM) {   // prefetch next K-tile into the other buffer
            const int nxt = cur ^ 1;
            load_lds16(z + aoff0 + k0, sA0 + nxt * 8192 + (wv * 2 + 0) * 1024);
            load_lds16(z + aoff1 + k0, sA0 + nxt * 8192 + (wv * 2 + 1) * 1024);
            load_lds16(z + boff0 + k0, sB0 + nxt * 8192 + (wv * 2 + 0) * 1024);
            load_lds16(z + boff1 + k0, sB0 + nxt * 8192 + (wv * 2 + 1) * 1024);
        }
        const char* cA = sA0 + cur * 8192;
        const char* cB = sB0 + cur * 8192;

        v8i af[2], bf[2];
        #pragma unroll
        for (int i = 0; i < 2; ++i) {
            const char* rowA = cA + (wr * 64 + i * 32 + m31) * 64;
            int4 lo = *(const int4*)(rowA + slot0);
            int4 hi = *(const int4*)(rowA + slot1);
            af[i][0] = lo.x; af[i][1] = lo.y; af[i][2] = lo.z; af[i][3] = lo.w;
            af[i][4] = hi.x; af[i][5] = hi.y; af[i][6] = hi.z; af[i][7] = hi.w;
            const char* rowB = cB + (wc * 64 + i * 32 + m31) * 64;
            int4 lob = *(const int4*)(rowB + slot0);
            int4 hib = *(const int4*)(rowB + slot1);
            bf[i][0] = lob.x; bf[i][1] = lob.y; bf[i][2] = lob.z; bf[i][3] = lob.w;
            bf[i][4] = hib.x; bf[i][5] = hib.y; bf[i][6] = hib.z; bf[i][7] = hib.w;
        }
        #pragma unroll
        for (int i = 0; i < 2; ++i)
            #pragma unroll
            for (int j = 0; j < 2; ++j)
                acc[i][j] = __builtin_amdgcn_mfma_scale_f32_32x32x64_f8f6f4(
                                af[i], bf[j], acc[i][j], 0, 0,
                                0, SCALE_ONE, 0, SCALE_ONE);
        __syncthreads();
        cur ^= 1;
    }

    // ---- Epilogue: C/D col = lane&31, row = (reg&3)+8*(reg>>2)+4*h ----
    #pragma unroll
    for (int i = 0; i < 2; ++i) {
        #pragma unroll
        for (int reg = 0; reg < 16; ++reg) {
            const int r  = rb + wr * 64 + i * 32 + (reg & 3) + 8 * (reg >> 2) + 4 * h;
            const int pc = (r + BATCH) & (TWO_B - 1);
            float local = 0.0f;
            #pragma unroll
            for (int j = 0; j < 2; ++j) {
                const int c = cb + wc * 64 + j * 32 + m31;
                const float s = acc[i][j][reg];
                if (c == pc)   // unique writer per r
                    __hip_atomic_store(&positives[r], s, __ATOMIC_RELAXED,
                                       __HIP_MEMORY_SCOPE_AGENT);
                local += (c == r) ? 0.0f : exp2f(s * INV_T_LOG2E);
            }
            // reduce across the 32 column-lanes (stays within the h-group)
            local += __shfl_xor(local, 1, 64);
            local += __shfl_xor(local, 2, 64);
            local += __shfl_xor(local, 4, 64);
            local += __shfl_xor(local, 8, 64);
            local += __shfl_xor(local, 16, 64);
            if (m31 == 0) atomicAdd(&rowsum[r], local);
        }
    }

    // ---- fence-free last-block finalize (R7/R8, proven) ----
    __shared__ int amLast;
    __syncthreads();
    if (tid == 0) {
        unsigned int old = __hip_atomic_fetch_add(counter, 1u, __ATOMIC_RELAXED,
                                                  __HIP_MEMORY_SCOPE_AGENT);
        amLast = (old == NBLK2 - 1);
    }
    __syncthreads();
    if (amLast) {
        float acc2 = 0.0f;
        for (int r = tid; r < TWO_B; r += 256) {
            float rs = __hip_atomic_load(&rowsum[r], __ATOMIC_RELAXED,
                                         __HIP_MEMORY_SCOPE_AGENT);
            float p  = __hip_atomic_load(&positives[r], __ATOMIC_RELAXED,
                                         __HIP_MEMORY_SCOPE_AGENT);
            acc2 += logf(rs) - p * INV_T;
        }
        #pragma unroll
        for (int off = 32; off; off >>= 1) acc2 += __shfl_down(acc2, off, 64);
        __shared__ float s_part[4];
        if ((tid & 63) == 0) s_part[tid >> 6] = acc2;
        __syncthreads();
        if (tid == 0)
            out[0] = (s_part[0] + s_part[1] + s_part[2] + s_part[3]) * (1.0f / TWO_B);
    }
}

extern "C" void kernel_launch(void* const* d_in, const int* in_sizes, int n_in,
                              void* d_out, int out_size, void* d_ws, size_t ws_size,
                              hipStream_t stream) {
    const float* feat = (const float*)d_in[0];
    char* ws = (char*)d_ws;

    // workspace: z fp8[4096][1024] (4 MB) | rowsum f32[4096] | positives f32[4096] | counter
    char* zq              = ws;
    float* rowsum         = (float*)(ws + (size_t)TWO_B * DIM);
    float* positives      = rowsum + TWO_B;
    unsigned int* counter = (unsigned int*)(positives + TWO_B);
    float* out            = (float*)d_out;

    normalize_kernel<<<TWO_B / 4, 256, 0, stream>>>(feat, zq, rowsum, counter);
    gemm_fused<<<NBLK2, 256, 0, stream>>>(zq, rowsum, positives, counter, out);
}

// Round 13
// 96.199 us; speedup vs baseline: 1.5757x; 1.3976x over previous
//
#include <hip/hip_runtime.h>
#include <hip/hip_bf16.h>
#include <math.h>

// Problem constants
#define BATCH   2048
#define TWO_B   4096
#define DIM     1024
#define NBLK4   256           // 16x16 grid of 256x256 tiles
// 1 / (0.07 * ln(2)) : exp(s/T) = exp2(s * INV_T_LOG2E)
#define INV_T_LOG2E 20.60991907f
#define INV_T       14.285714285714286f

typedef float f32x4 __attribute__((ext_vector_type(4)));
typedef long  i64x2 __attribute__((ext_vector_type(2)));

__device__ __forceinline__ void load_lds16(const void* g, void* l) {
    __builtin_amdgcn_global_load_lds(
        (const __attribute__((address_space(1))) void*)g,
        (__attribute__((address_space(3))) void*)l,
        16, 0, 0);
}

// ---------------------------------------------------------------------------
// Kernel 1: L2-normalize 4096 rows -> fp8 e4m3 z[4096][1024] (4 MB).
// Wave-per-row; zero-inits rowsum + completion counter. No fences.
// ---------------------------------------------------------------------------
__global__ __launch_bounds__(256) void normalize_kernel(
        const float* __restrict__ feat, char* __restrict__ z,
        float* __restrict__ rowsum, unsigned int* __restrict__ counter) {
    const int lane = threadIdx.x & 63;
    const int row  = blockIdx.x * 4 + (threadIdx.x >> 6);
    if (lane == 0) rowsum[row] = 0.0f;
    if (blockIdx.x == 0 && threadIdx.x == 0) *counter = 0u;

    const float* src = feat + (row < BATCH ? (size_t)row * (2 * DIM)
                                           : (size_t)(row - BATCH) * (2 * DIM) + DIM);
    float4 v[4];
    float ss = 0.0f;
    #pragma unroll
    for (int t = 0; t < 4; ++t) {
        v[t] = ((const float4*)src)[t * 64 + lane];
        ss += v[t].x * v[t].x + v[t].y * v[t].y + v[t].z * v[t].z + v[t].w * v[t].w;
    }
    #pragma unroll
    for (int off = 32; off; off >>= 1) ss += __shfl_xor(ss, off, 64);
    const float scale = 1.0f / fmaxf(sqrtf(ss), 1e-12f);
    int4 o;
    int* op = (int*)&o;
    #pragma unroll
    for (int t = 0; t < 4; ++t) {
        int lo = __builtin_amdgcn_cvt_pk_fp8_f32(v[t].x * scale, v[t].y * scale, 0, false);
        op[t]  = __builtin_amdgcn_cvt_pk_fp8_f32(v[t].z * scale, v[t].w * scale, lo, true);
    }
    ((int4*)(z + (size_t)row * DIM))[lane] = o;   // 64 lanes x 16 B = one row
}

// ---------------------------------------------------------------------------
// Kernel 2: sim = z z^T in fp8 e4m3 (plain 16x16x32 MFMA — R12's MX variant
// regressed on VGPR+conflicts). R13 = R8's proven shell scaled to 256x256
// tiles, 8 waves (512 thr), BK=64 dbuf (64 KB LDS), 256 blocks = 1/CU:
// staged bytes 256 MB -> 134 MB (the affine-model lever), LDS reads
// 16 -> 8 B per MFMA. Wave wv: rows (wv&3)*64, cols (wv>>2)*128.
// Unchanged proven pieces: XOR swizzle (0 conflicts, 64-B rows), XCD 4x8
// region swizzle (3 MB < 4 MB L2), shfl epilogue (R6), fence-free finalize.
// ---------------------------------------------------------------------------
__global__ __launch_bounds__(512) void gemm_fused(
        const char* __restrict__ z,
        float* __restrict__ rowsum,
        float* __restrict__ positives,
        unsigned int* __restrict__ counter,
        float* __restrict__ out) {
    __shared__ char smem[65536];     // buf: [sA 16K | sB 16K] x2

    // XCD-aware swizzle: id&7 = round-robin XCD; 4x8-tile region per XCD
    const int bid = blockIdx.x;
    const int xcd = bid & 7;
    const int t5  = bid >> 3;                   // 0..31 within region
    const int by  = (xcd >> 1) * 4 + (t5 & 3);
    const int bx  = (xcd & 1) * 8 + (t5 >> 2);
    const int rb  = by * 256;
    const int cb  = bx * 256;

    const int tid  = threadIdx.x;
    const int lane = tid & 63;
    const int wv   = tid >> 6;       // wave 0..7
    const int wr   = wv & 3;         // wave row (0..3) -> 64-row subtile
    const int wc   = wv >> 2;        // wave col (0..1) -> 128-col subtile
    const int q    = lane >> 4;      // quad 0..3
    const int mn   = lane & 15;

    f32x4 acc[4][8] = {};

    const int lrow  = lane >> 2;                       // row within 16-row chunk
    const int lsegb = ((lane & 3) ^ ((lane >> 3) & 3)) * 16;   // fetch-side XOR swizzle
    const int rslot = (q ^ ((mn >> 1) & 3)) * 16;      // byte offset in 64-B row

    // staging: 32 chunks of 16 rows x 64 B (A: ci 0..15, B: ci 16..31);
    // wave wv stages ci = 4wv..4wv+3.
    size_t goff[4];
    int    loff[4];
    #pragma unroll
    for (int t = 0; t < 4; ++t) {
        const int ci = wv * 4 + t;
        const bool isB = ci >= 16;
        const int  cc  = ci & 15;
        goff[t] = (size_t)((isB ? cb : rb) + cc * 16 + lrow) * DIM + lsegb;
        loff[t] = (isB ? 16384 : 0) + cc * 1024;
    }

    // preload K-tile 0 into buffer 0
    #pragma unroll
    for (int t = 0; t < 4; ++t)
        load_lds16(z + goff[t], smem + loff[t]);
    __syncthreads();

    int cur = 0;
    for (int k0 = 64; k0 <= DIM; k0 += 64) {
        if (k0 < DIM) {   // prefetch next K-tile into the other buffer
            const int nxt = cur ^ 1;
            #pragma unroll
            for (int t = 0; t < 4; ++t)
                load_lds16(z + goff[t] + k0, smem + nxt * 32768 + loff[t]);
        }
        const char* cA = smem + cur * 32768;
        const char* cB = cA + 16384;

        i64x2 af[4], bf[8];
        #pragma unroll
        for (int i = 0; i < 4; ++i)
            af[i] = *(const i64x2*)&cA[(wr * 64 + i * 16 + mn) * 64 + rslot];
        #pragma unroll
        for (int j = 0; j < 8; ++j)
            bf[j] = *(const i64x2*)&cB[(wc * 128 + j * 16 + mn) * 64 + rslot];
        #pragma unroll
        for (int i = 0; i < 4; ++i)
            #pragma unroll
            for (int j = 0; j < 8; ++j) {
                acc[i][j] = __builtin_amdgcn_mfma_f32_16x16x32_fp8_fp8(
                                af[i].x, bf[j].x, acc[i][j], 0, 0, 0);
                acc[i][j] = __builtin_amdgcn_mfma_f32_16x16x32_fp8_fp8(
                                af[i].y, bf[j].y, acc[i][j], 0, 0, 0);
            }
        __syncthreads();
        cur ^= 1;
    }

    // ---- Epilogue (R6-style shfl; C/D col = lane&15, row = q*4 + reg) ----
    #pragma unroll
    for (int i = 0; i < 4; ++i) {
        #pragma unroll
        for (int reg = 0; reg < 4; ++reg) {
            const int r  = rb + wr * 64 + i * 16 + q * 4 + reg;
            const int pc = (r + BATCH) & (TWO_B - 1);
            float local = 0.0f;
            #pragma unroll
            for (int j = 0; j < 8; ++j) {
                const int c = cb + wc * 128 + j * 16 + mn;
                const float s = acc[i][j][reg];
                if (c == pc)   // unique writer per r
                    __hip_atomic_store(&positives[r], s, __ATOMIC_RELAXED,
                                       __HIP_MEMORY_SCOPE_AGENT);
                local += (c == r) ? 0.0f : exp2f(s * INV_T_LOG2E);
            }
            local += __shfl_xor(local, 1, 64);
            local += __shfl_xor(local, 2, 64);
            local += __shfl_xor(local, 4, 64);
            local += __shfl_xor(local, 8, 64);
            if (mn == 0) atomicAdd(&rowsum[r], local);
        }
    }

    // ---- fence-free last-block finalize (R7/R8, proven) ----
    __shared__ int amLast;
    __syncthreads();
    if (tid == 0) {
        unsigned int old = __hip_atomic_fetch_add(counter, 1u, __ATOMIC_RELAXED,
                                                  __HIP_MEMORY_SCOPE_AGENT);
        amLast = (old == NBLK4 - 1);
    }
    __syncthreads();
    if (amLast) {
        float acc2 = 0.0f;
        for (int r = tid; r < TWO_B; r += 512) {
            float rs = __hip_atomic_load(&rowsum[r], __ATOMIC_RELAXED,
                                         __HIP_MEMORY_SCOPE_AGENT);
            float p  = __hip_atomic_load(&positives[r], __ATOMIC_RELAXED,
                                         __HIP_MEMORY_SCOPE_AGENT);
            acc2 += logf(rs) - p * INV_T;
        }
        #pragma unroll
        for (int off = 32; off; off >>= 1) acc2 += __shfl_down(acc2, off, 64);
        __shared__ float s_part[8];
        if ((tid & 63) == 0) s_part[tid >> 6] = acc2;
        __syncthreads();
        if (tid == 0) {
            float tot = 0.0f;
            #pragma unroll
            for (int w = 0; w < 8; ++w) tot += s_part[w];
            out[0] = tot * (1.0f / TWO_B);
        }
    }
}

extern "C" void kernel_launch(void* const* d_in, const int* in_sizes, int n_in,
                              void* d_out, int out_size, void* d_ws, size_t ws_size,
                              hipStream_t stream) {
    const float* feat = (const float*)d_in[0];
    char* ws = (char*)d_ws;

    // workspace: z fp8[4096][1024] (4 MB) | rowsum f32[4096] | positives f32[4096] | counter
    char* zq              = ws;
    float* rowsum         = (float*)(ws + (size_t)TWO_B * DIM);
    float* positives      = rowsum + TWO_B;
    unsigned int* counter = (unsigned int*)(positives + TWO_B);
    float* out            = (float*)d_out;

    normalize_kernel<<<TWO_B / 4, 256, 0, stream>>>(feat, zq, rowsum, counter);
    gemm_fused<<<NBLK4, 512, 0, stream>>>(zq, rowsum, positives, counter, out);
}